// Round 3
// baseline (103.386 us; speedup 1.0000x reference)
//
#include <hip/hip_runtime.h>
#include <hip/hip_bf16.h>

#define NPATCH 196

// One block per image. Each block redundantly rebuilds the fixed (param-only)
// observable A_w = Re(V^dag Z_w V) in LDS, then contracts it with each patch's
// real product state. Output is FLOAT32 (reference returns f32 log_softmax).
__global__ __launch_bounds__(256) void quanv_fused(const float* __restrict__ x,
                                                   const float* __restrict__ P,
                                                   const float* __restrict__ W,
                                                   const float* __restrict__ bias,
                                                   float* __restrict__ out) {
  __shared__ float Vr[16][16];   // [row k][col i]
  __shared__ float Vi[16][16];
  __shared__ float4 A4[16][16];  // (i<=j valid) off-diag pre-doubled; .x=w0 .y=w1 .z=w2 .w=w3
  __shared__ float red[NPATCH * 10];
  __shared__ float part2[40];
  __shared__ float logits[10];
  __shared__ float snorm;
  const int tid = threadIdx.x;
  const int b = blockIdx.x;

  // ---- phase 1: simulate column `tid` of V (wire 0 = MSB, bit 3) ----
  if (tid < 16) {
    float sr[16], si[16];
#pragma unroll
    for (int i = 0; i < 16; ++i) { sr[i] = (i == tid) ? 1.0f : 0.0f; si[i] = 0.0f; }
#pragma unroll
    for (int d = 0; d < 2; ++d) {
#pragma unroll
      for (int w = 0; w < 4; ++w) {
        const int m = 8 >> w;
        float th, c, s;
        // RX: [[c, -i s],[-i s, c]]
        th = P[(d * 4 + w) * 3 + 0];
        c = cosf(0.5f * th); s = sinf(0.5f * th);
#pragma unroll
        for (int i = 0; i < 16; ++i) if (!(i & m)) {
          const int j = i | m;
          const float r0 = sr[i], i0 = si[i], r1 = sr[j], i1 = si[j];
          sr[i] = c * r0 + s * i1; si[i] = c * i0 - s * r1;
          sr[j] = c * r1 + s * i0; si[j] = c * i1 - s * r0;
        }
        // RY: [[c, -s],[s, c]]
        th = P[(d * 4 + w) * 3 + 1];
        c = cosf(0.5f * th); s = sinf(0.5f * th);
#pragma unroll
        for (int i = 0; i < 16; ++i) if (!(i & m)) {
          const int j = i | m;
          const float r0 = sr[i], i0 = si[i], r1 = sr[j], i1 = si[j];
          sr[i] = c * r0 - s * r1; si[i] = c * i0 - s * i1;
          sr[j] = s * r0 + c * r1; si[j] = s * i0 + c * i1;
        }
        // RZ: diag(e^{-i th/2}, e^{+i th/2})
        th = P[(d * 4 + w) * 3 + 2];
        c = cosf(0.5f * th); s = sinf(0.5f * th);
#pragma unroll
        for (int i = 0; i < 16; ++i) if (!(i & m)) {
          const int j = i | m;
          const float r0 = sr[i], i0 = si[i], r1 = sr[j], i1 = si[j];
          sr[i] = c * r0 + s * i0; si[i] = c * i0 - s * r0;
          sr[j] = c * r1 - s * i1; si[j] = c * i1 + s * r1;
        }
      }
      // CNOT ring (0,1),(1,2),(2,3),(3,0): control set -> flip target
#pragma unroll
      for (int g = 0; g < 4; ++g) {
        const int mc = 8 >> g, mt = 8 >> ((g + 1) & 3);
#pragma unroll
        for (int i = 0; i < 16; ++i) if ((i & mc) && !(i & mt)) {
          const int j = i | mt;
          float t;
          t = sr[i]; sr[i] = sr[j]; sr[j] = t;
          t = si[i]; si[i] = si[j]; si[j] = t;
        }
      }
    }
#pragma unroll
    for (int k = 0; k < 16; ++k) { Vr[k][tid] = sr[k]; Vi[k][tid] = si[k]; }
  }
  __syncthreads();

  // ---- phase 2: A_w[i][j] = sum_k z_w(k) * Re(conj(V[k][i]) V[k][j]) ----
  {
    const int i = tid >> 4, j = tid & 15;
    float s0 = 0, s1 = 0, s2 = 0, s3 = 0;
#pragma unroll
    for (int k = 0; k < 16; ++k) {
      const float pr = Vr[k][i] * Vr[k][j] + Vi[k][i] * Vi[k][j];
      s0 += (k & 8) ? -pr : pr;
      s1 += (k & 4) ? -pr : pr;
      s2 += (k & 2) ? -pr : pr;
      s3 += (k & 1) ? -pr : pr;
    }
    const float mult = (i == j) ? 1.0f : 2.0f;  // fold symmetry doubling
    A4[i][j] = make_float4(s0 * mult, s1 * mult, s2 * mult, s3 * mult);
  }
  __syncthreads();

  // ---- phase 3: per-patch contraction ----
  if (tid < NPATCH) {
    const int pi = tid / 14, pj = tid - pi * 14;
    const float* px = x + b * 784 + pi * 56 + pj * 2;
    const float2 r0 = *reinterpret_cast<const float2*>(px);
    const float2 r1 = *reinterpret_cast<const float2*>(px + 28);
    float hc0, hs0, hc1, hs1, hc2, hs2, hc3, hs3;
    sincosf(0.5f * r0.x, &hs0, &hc0);
    sincosf(0.5f * r0.y, &hs1, &hc1);
    sincosf(0.5f * r1.x, &hs2, &hc2);
    sincosf(0.5f * r1.y, &hs3, &hc3);
    const float p01[4] = {hc0 * hc1, hc0 * hs1, hs0 * hc1, hs0 * hs1};
    const float p23[4] = {hc2 * hc3, hc2 * hs3, hs2 * hc3, hs2 * hs3};
    float psi[16];
#pragma unroll
    for (int i = 0; i < 16; ++i) psi[i] = p01[i >> 2] * p23[i & 3];

    float f0 = 0, f1 = 0, f2 = 0, f3 = 0;
#pragma unroll
    for (int i = 0; i < 16; ++i) {
#pragma unroll
      for (int j = i; j < 16; ++j) {
        const float pp = psi[i] * psi[j];
        const float4 a = A4[i][j];
        f0 += a.x * pp; f1 += a.y * pp; f2 += a.z * pp; f3 += a.w * pp;
      }
    }
    // per-class partials: feature index = tid*4 + w
    const float* Wp = W + tid * 4;
#pragma unroll
    for (int k = 0; k < 10; ++k) {
      const float4 wv = *reinterpret_cast<const float4*>(Wp + k * 784);
      red[tid * 10 + k] = f0 * wv.x + f1 * wv.y + f2 * wv.z + f3 * wv.w;
    }
  }
  __syncthreads();

  // ---- phase 4: reduce 196 patches -> 10 logits (196 = 4*49) ----
  if (tid < 40) {
    const int k = tid >> 2, q = tid & 3;
    float s = 0;
    const int p0 = q * 49;
    for (int p = p0; p < p0 + 49; ++p) s += red[p * 10 + k];
    part2[tid] = s;
  }
  __syncthreads();
  if (tid < 10)
    logits[tid] = part2[tid * 4] + part2[tid * 4 + 1] + part2[tid * 4 + 2] +
                  part2[tid * 4 + 3] + bias[tid];
  __syncthreads();
  if (tid == 0) {
    float m = logits[0];
#pragma unroll
    for (int k = 1; k < 10; ++k) m = fmaxf(m, logits[k]);
    float se = 0;
#pragma unroll
    for (int k = 0; k < 10; ++k) se += expf(logits[k] - m);
    snorm = m + logf(se);
  }
  __syncthreads();
  if (tid < 10) out[b * 10 + tid] = logits[tid] - snorm;
}

extern "C" void kernel_launch(void* const* d_in, const int* in_sizes, int n_in,
                              void* d_out, int out_size, void* d_ws, size_t ws_size,
                              hipStream_t stream) {
  const float* x = (const float*)d_in[0];     // (B,1,28,28) f32
  const float* P = (const float*)d_in[1];     // (2,4,3) f32
  const float* W = (const float*)d_in[2];     // (10,784) f32
  const float* bias = (const float*)d_in[3];  // (10,) f32
  float* out = (float*)d_out;                 // (B,10) f32
  const int B = out_size / 10;

  quanv_fused<<<B, 256, 0, stream>>>(x, P, W, bias, out);
}